// Round 11
// baseline (37.494 us; speedup 1.0000x reference)
//
#include <hip/hip_runtime.h>

typedef float f32x2 __attribute__((ext_vector_type(2)));

// Separable DCT constants
#define K4 0.353553391f
#define K1 0.490392640f
#define K3 0.415734806f
#define K5 0.277785117f
#define K7 0.097545161f
#define K2 0.461939766f
#define K6 0.191341716f

// Reference quant: qt_y(u,v) = Yorig[v][u]; stored transposed so row u is contiguous in v.
__device__ __align__(16) const float YQT[64] = {
    16.f, 12.f, 14.f, 14.f,  18.f,  24.f,  49.f,  72.f,
    11.f, 12.f, 13.f, 17.f,  22.f,  35.f,  64.f,  92.f,
    10.f, 14.f, 16.f, 22.f,  37.f,  55.f,  78.f,  95.f,
    16.f, 19.f, 24.f, 29.f,  56.f,  64.f,  87.f,  98.f,
    24.f, 26.f, 40.f, 51.f,  68.f,  81.f, 103.f, 112.f,
    40.f, 58.f, 57.f, 87.f, 109.f, 104.f, 121.f, 100.f,
    51.f, 60.f, 69.f, 80.f, 103.f, 113.f, 120.f, 103.f,
    61.f, 55.f, 56.f, 62.f,  77.f,  92.f, 101.f,  99.f
};
// Correctly-rounded reciprocals (compile-time IEEE division), same layout.
__device__ __align__(16) const float RYQT[64] = {
    1.f/16.f, 1.f/12.f, 1.f/14.f, 1.f/14.f, 1.f/18.f,  1.f/24.f,  1.f/49.f,  1.f/72.f,
    1.f/11.f, 1.f/12.f, 1.f/13.f, 1.f/17.f, 1.f/22.f,  1.f/35.f,  1.f/64.f,  1.f/92.f,
    1.f/10.f, 1.f/14.f, 1.f/16.f, 1.f/22.f, 1.f/37.f,  1.f/55.f,  1.f/78.f,  1.f/95.f,
    1.f/16.f, 1.f/19.f, 1.f/24.f, 1.f/29.f, 1.f/56.f,  1.f/64.f,  1.f/87.f,  1.f/98.f,
    1.f/24.f, 1.f/26.f, 1.f/40.f, 1.f/51.f, 1.f/68.f,  1.f/81.f,  1.f/103.f, 1.f/112.f,
    1.f/40.f, 1.f/58.f, 1.f/57.f, 1.f/87.f, 1.f/109.f, 1.f/104.f, 1.f/121.f, 1.f/100.f,
    1.f/51.f, 1.f/60.f, 1.f/69.f, 1.f/80.f, 1.f/103.f, 1.f/113.f, 1.f/120.f, 1.f/103.f,
    1.f/61.f, 1.f/55.f, 1.f/56.f, 1.f/62.f, 1.f/77.f,  1.f/92.f,  1.f/101.f, 1.f/99.f
};
// Chroma table (symmetric) + reciprocals.
__device__ __align__(16) const float CQ[64] = {
    17.f, 18.f, 24.f, 47.f, 99.f, 99.f, 99.f, 99.f,
    18.f, 21.f, 26.f, 66.f, 99.f, 99.f, 99.f, 99.f,
    24.f, 26.f, 56.f, 99.f, 99.f, 99.f, 99.f, 99.f,
    47.f, 66.f, 99.f, 99.f, 99.f, 99.f, 99.f, 99.f,
    99.f, 99.f, 99.f, 99.f, 99.f, 99.f, 99.f, 99.f,
    99.f, 99.f, 99.f, 99.f, 99.f, 99.f, 99.f, 99.f,
    99.f, 99.f, 99.f, 99.f, 99.f, 99.f, 99.f, 99.f,
    99.f, 99.f, 99.f, 99.f, 99.f, 99.f, 99.f, 99.f
};
__device__ __align__(16) const float RCQ[64] = {
    1.f/17.f, 1.f/18.f, 1.f/24.f, 1.f/47.f, 1.f/99.f, 1.f/99.f, 1.f/99.f, 1.f/99.f,
    1.f/18.f, 1.f/21.f, 1.f/26.f, 1.f/66.f, 1.f/99.f, 1.f/99.f, 1.f/99.f, 1.f/99.f,
    1.f/24.f, 1.f/26.f, 1.f/56.f, 1.f/99.f, 1.f/99.f, 1.f/99.f, 1.f/99.f, 1.f/99.f,
    1.f/47.f, 1.f/66.f, 1.f/99.f, 1.f/99.f, 1.f/99.f, 1.f/99.f, 1.f/99.f, 1.f/99.f,
    1.f/99.f, 1.f/99.f, 1.f/99.f, 1.f/99.f, 1.f/99.f, 1.f/99.f, 1.f/99.f, 1.f/99.f,
    1.f/99.f, 1.f/99.f, 1.f/99.f, 1.f/99.f, 1.f/99.f, 1.f/99.f, 1.f/99.f, 1.f/99.f,
    1.f/99.f, 1.f/99.f, 1.f/99.f, 1.f/99.f, 1.f/99.f, 1.f/99.f, 1.f/99.f, 1.f/99.f,
    1.f/99.f, 1.f/99.f, 1.f/99.f, 1.f/99.f, 1.f/99.f, 1.f/99.f, 1.f/99.f, 1.f/99.f
};

// fma helpers: scalar -> v_fma_f32, f32x2 -> v_pk_fma_f32 (bit-identical per half)
__device__ __forceinline__ float gfma(float a, float b, float c) { return fmaf(a, b, c); }
__device__ __forceinline__ f32x2 gfma(f32x2 a, f32x2 b, f32x2 c) { return __builtin_elementwise_fma(a, b, c); }
__device__ __forceinline__ f32x2 gfma(float a, f32x2 b, f32x2 c) { return __builtin_elementwise_fma((f32x2){a, a}, b, c); }

// clamp to [0,1] via v_med3_f32 — value-identical to fminf(fmaxf(x,0),1) for non-NaN
__device__ __forceinline__ float clamp01(float x) { return __builtin_amdgcn_fmed3f(x, 0.f, 1.f); }

// 8-point DCT-II butterfly (frozen arithmetic since R4).
template <typename T>
__device__ __forceinline__ void dct8(const T x[8], T X[8]) {
    const T a0 = x[0] + x[7], a1 = x[1] + x[6], a2 = x[2] + x[5], a3 = x[3] + x[4];
    const T d0 = x[0] - x[7], d1 = x[1] - x[6], d2 = x[2] - x[5], d3 = x[3] - x[4];
    const T e0 = a0 + a3, e1 = a1 + a2, f0 = a0 - a3, f1 = a1 - a2;
    X[0] = K4 * (e0 + e1);
    X[4] = K4 * (e0 - e1);
    X[2] = gfma(K6, f1, K2 * f0);
    X[6] = gfma(-K2, f1, K6 * f0);
    X[1] = gfma(K7, d3, gfma(K5, d2, gfma(K3, d1, K1 * d0)));
    X[3] = gfma(-K5, d3, gfma(-K1, d2, gfma(-K7, d1, K3 * d0)));
    X[5] = gfma(K3, d3, gfma(K7, d2, gfma(-K1, d1, K5 * d0)));
    X[7] = gfma(-K1, d3, gfma(K3, d2, gfma(-K5, d1, K7 * d0)));
}

template <typename T>
__device__ __forceinline__ void idct8(const T X[8], T x[8]) {
    const T g0 = K4 * (X[0] + X[4]);
    const T g1 = K4 * (X[0] - X[4]);
    const T E0 = gfma(K6, X[6], gfma(K2, X[2], g0));
    const T E1 = gfma(-K2, X[6], gfma(K6, X[2], g1));
    const T E2 = gfma(K2, X[6], gfma(-K6, X[2], g1));
    const T E3 = gfma(-K6, X[6], gfma(-K2, X[2], g0));
    const T O0 = gfma(K7, X[7], gfma(K5, X[5], gfma(K3, X[3], K1 * X[1])));
    const T O1 = gfma(-K5, X[7], gfma(-K1, X[5], gfma(-K7, X[3], K3 * X[1])));
    const T O2 = gfma(K3, X[7], gfma(K7, X[5], gfma(-K1, X[3], K5 * X[1])));
    const T O3 = gfma(-K1, X[7], gfma(K3, X[5], gfma(-K5, X[3], K7 * X[1])));
    x[0] = E0 + O0;  x[7] = E0 - O0;
    x[1] = E1 + O1;  x[6] = E1 - O1;
    x[2] = E2 + O2;  x[5] = E2 - O2;
    x[3] = E3 + O3;  x[4] = E3 - O3;
}

// Exact RN(s/qt) via Markstein refinement (bit-identical to IEEE div) + rint + dequant.
__device__ __forceinline__ f32x2 quant2(f32x2 sv, f32x2 qt, f32x2 rq) {
    const f32x2 q0 = sv * rq;
    const f32x2 e  = gfma(-qt, q0, sv);
    const f32x2 q  = gfma(rq, e, q0);
    const f32x2 n  = {rintf(q.x), rintf(q.y)};
    return n * qt;
}

// Scheduler-only ordering point (R8/R10-verified correct for the wave-local
// LDS union: absmax bit-identical with SB-only fencing).
#define SB() __builtin_amdgcn_sched_barrier(0)

#define YW 68   // Y row stride (floats):    column access 2-way (free), row float4 bank-perfect
#define CW 70   // chroma row stride (f32x2): column 8B-contig (free), row float4 bank-perfect

// 128-thread blocks (2 waves): finer scheduling quantum than 256 — waves never
// communicate across the block (all LDS traffic wave-private), so smaller blocks
// only improve CU packing. LDS 8960 B/block; 16 blocks/CU x 2 waves = 32 waves/CU
// reachable. __launch_bounds__(128,8): VGPR cap 64 (R7 used 32-60).
__global__ __launch_bounds__(128, 8) void diffjpeg_kernel(const float* __restrict__ in,
                                                          float* __restrict__ out)
{
    // PER-WAVE private chunk: 8 x 70 f32x2 = 4480 B; the wave's Y view (float,
    // stride 68) aliases the same chunk -> union is wave-local; wave-local
    // ordering is supplied by the per-wave in-order DS pipe.
    __shared__ __align__(16) f32x2 lds[2][8][CW];

    const int t  = threadIdx.x;
    const int l  = t & 63;
    const int wv = t >> 6;          // 0..1
    const int b8 = (l >> 3) * 8;    // block's column offset within strip
    const int rr = l & 7;           // within-block row index for row pass

    f32x2 (*plc)[CW] = lds[wv];            // chroma view: [8][70] f32x2
    float* ply = (float*)&lds[wv][0][0];   // Y view: [8][68] floats (aliases chunk)

    // 8192 blocks: 256 per image (32 row-pairs x 8 col-tiles); each wave owns
    // one 64x8 strip.
    const int bid  = blockIdx.x;
    const int img  = bid >> 8;       // 256 blocks per image
    const int rem  = bid & 255;
    const int trow = rem >> 3;       // 0..31 (16-row slab)
    const int tcol = rem & 7;        // 0..7  (64-col tile)
    const size_t HW = (size_t)512 * 512;
    const size_t sbase = (size_t)img * 3 * HW + (size_t)(trow * 16 + wv * 8) * 512 + (size_t)(tcol * 64);
    const float* __restrict__ pin  = in  + sbase + l;
    float* __restrict__       pout = out + sbase + l;

    // ---- Load strip column + RGB->YCbCr (identical arithmetic to R4) ----
    float rv[8], gv[8], bv[8];
    #pragma unroll
    for (int x = 0; x < 8; ++x) rv[x] = pin[(size_t)x * 512];
    #pragma unroll
    for (int x = 0; x < 8; ++x) gv[x] = pin[HW + (size_t)x * 512];
    #pragma unroll
    for (int x = 0; x < 8; ++x) bv[x] = pin[2 * HW + (size_t)x * 512];

    float yv[8];
    f32x2 cc[8];
    #pragma unroll
    for (int x = 0; x < 8; ++x) {
        const float r = clamp01(rv[x]);
        const float g = clamp01(gv[x]);
        const float b = clamp01(bv[x]);
        const float Y = fmaf(76.245f, r, fmaf(149.685f, g, 29.07f * b));  // 255*y
        yv[x] = Y - 128.f;
        const f32x2 tbr = gfma(255.f, (f32x2){b, r}, (f32x2){-Y, -Y});
        cc[x] = gfma((f32x2){0.564f, 0.713f}, tbr, (f32x2){-0.5f, -0.5f}); // {cb,cr}
    }

    // ==================== Y plane (scalar), full chain ====================
    float sy[8];
    {
        // column DCT -> LDS
        float X0[8];
        dct8(yv, X0);
        #pragma unroll
        for (int u = 0; u < 8; ++u) ply[u * YW + l] = X0[u];
        SB();

        // row pass: row DCT + quant/round/dequant + row IDCT (float4 LDS I/O)
        {
            const float4* yq4  = (const float4*)&YQT[rr * 8];
            const float4* ryq4 = (const float4*)&RYQT[rr * 8];
            const float4 yqa = yq4[0],  yqb = yq4[1];
            const float4 rya = ryq4[0], ryb = ryq4[1];
            const float yq[8]  = {yqa.x, yqa.y, yqa.z, yqa.w, yqb.x, yqb.y, yqb.z, yqb.w};
            const float ryq[8] = {rya.x, rya.y, rya.z, rya.w, ryb.x, ryb.y, ryb.z, ryb.w};

            float4* rp = (float4*)(ply + rr * YW + b8);
            const float4 a0 = rp[0];
            const float4 a1 = rp[1];
            const float T[8] = {a0.x, a0.y, a0.z, a0.w, a1.x, a1.y, a1.z, a1.w};
            float S[8];
            dct8(T, S);
            float Dq[8];
            #pragma unroll
            for (int i = 0; i < 4; ++i) {
                const f32x2 d = quant2((f32x2){S[2*i], S[2*i+1]},
                                       (f32x2){yq[2*i], yq[2*i+1]},
                                       (f32x2){ryq[2*i], ryq[2*i+1]});
                Dq[2*i] = d.x; Dq[2*i+1] = d.y;
            }
            float o[8];
            idct8(Dq, o);
            rp[0] = make_float4(o[0], o[1], o[2], o[3]);
            rp[1] = make_float4(o[4], o[5], o[6], o[7]);
        }
        SB();

        // column IDCT -> sy registers
        float Xy[8];
        #pragma unroll
        for (int u = 0; u < 8; ++u) Xy[u] = ply[u * YW + l];
        idct8(Xy, sy);
    }
    SB();   // WAR (wave-local): Y col reads ordered before chroma writes reuse the chunk

    // ==================== Chroma (cb,cr packed f32x2), full chain ====================
    f32x2 sc[8];
    {
        // column DCT -> LDS (8B-contiguous per lane => conflict-free)
        f32x2 XC[8];
        dct8(cc, XC);
        #pragma unroll
        for (int u = 0; u < 8; ++u) plc[u][l] = XC[u];
        SB();

        // row pass, fully packed
        {
            const float4* cq4  = (const float4*)&CQ[rr * 8];
            const float4* rcq4 = (const float4*)&RCQ[rr * 8];
            const float4 cqa = cq4[0],  cqb = cq4[1];
            const float4 rca = rcq4[0], rcb4 = rcq4[1];
            const float cq[8]  = {cqa.x, cqa.y, cqa.z, cqa.w, cqb.x, cqb.y, cqb.z, cqb.w};
            const float rcq[8] = {rca.x, rca.y, rca.z, rca.w, rcb4.x, rcb4.y, rcb4.z, rcb4.w};

            float4* rp = (float4*)&plc[rr][b8];
            const float4 p0 = rp[0], p1 = rp[1], p2 = rp[2], p3 = rp[3];
            const f32x2 T[8] = {{p0.x, p0.y}, {p0.z, p0.w}, {p1.x, p1.y}, {p1.z, p1.w},
                                {p2.x, p2.y}, {p2.z, p2.w}, {p3.x, p3.y}, {p3.z, p3.w}};
            f32x2 S[8];
            dct8(T, S);
            f32x2 Dq[8];
            #pragma unroll
            for (int v = 0; v < 8; ++v)
                Dq[v] = quant2(S[v], (f32x2){cq[v], cq[v]}, (f32x2){rcq[v], rcq[v]});
            f32x2 o[8];
            idct8(Dq, o);
            rp[0] = make_float4(o[0].x, o[0].y, o[1].x, o[1].y);
            rp[1] = make_float4(o[2].x, o[2].y, o[3].x, o[3].y);
            rp[2] = make_float4(o[4].x, o[4].y, o[5].x, o[5].y);
            rp[3] = make_float4(o[6].x, o[6].y, o[7].x, o[7].y);
        }
        SB();

        // column IDCT -> sc registers
        f32x2 Xc[8];
        #pragma unroll
        for (int u = 0; u < 8; ++u) Xc[u] = plc[u][l];
        idct8(Xc, sc);
    }

    // ---- YCbCr->RGB + clip + nt store (identical arithmetic to R4) ----
    {
        constexpr float inv255 = 1.0f / 255.0f;
        constexpr float Kr = 0.504711754f;
        constexpr float Kg = 0.499886280f;
        constexpr float Kb = 0.505437240f;
        #pragma unroll
        for (int x = 0; x < 8; ++x) {
            const float scb = sc[x].x;
            const float scr = sc[x].y;
            const f32x2 inner = gfma((f32x2){1.403f, 1.773f}, (f32x2){scr, scb},
                                     (f32x2){sy[x], sy[x]});
            const f32x2 rb = gfma(inv255, inner, (f32x2){Kr, Kb});
            const float gg = fmaf(inv255, fmaf(-0.714f, scr, fmaf(-0.344f, scb, sy[x])), Kg);
            __builtin_nontemporal_store(clamp01(rb.x), pout + (size_t)x * 512);
            __builtin_nontemporal_store(clamp01(gg),   pout + HW + (size_t)x * 512);
            __builtin_nontemporal_store(clamp01(rb.y), pout + 2 * HW + (size_t)x * 512);
        }
    }
}

extern "C" void kernel_launch(void* const* d_in, const int* in_sizes, int n_in,
                              void* d_out, int out_size, void* d_ws, size_t ws_size,
                              hipStream_t stream) {
    const float* in = (const float*)d_in[0];
    float* out = (float*)d_out;
    const int B = in_sizes[0] / (3 * 512 * 512);   // 32
    const int grid = B * 256;                       // 256 two-wave blocks per image
    diffjpeg_kernel<<<grid, 128, 0, stream>>>(in, out);
}

// Round 12
// 34.922 us; speedup vs baseline: 1.0737x; 1.0737x over previous
//
#include <hip/hip_runtime.h>

typedef float f32x2 __attribute__((ext_vector_type(2)));

// Separable DCT constants
#define K4 0.353553391f
#define K1 0.490392640f
#define K3 0.415734806f
#define K5 0.277785117f
#define K7 0.097545161f
#define K2 0.461939766f
#define K6 0.191341716f

// Reference quant: qt_y(u,v) = Yorig[v][u]; stored transposed so row u is contiguous in v.
__device__ __align__(16) const float YQT[64] = {
    16.f, 12.f, 14.f, 14.f,  18.f,  24.f,  49.f,  72.f,
    11.f, 12.f, 13.f, 17.f,  22.f,  35.f,  64.f,  92.f,
    10.f, 14.f, 16.f, 22.f,  37.f,  55.f,  78.f,  95.f,
    16.f, 19.f, 24.f, 29.f,  56.f,  64.f,  87.f,  98.f,
    24.f, 26.f, 40.f, 51.f,  68.f,  81.f, 103.f, 112.f,
    40.f, 58.f, 57.f, 87.f, 109.f, 104.f, 121.f, 100.f,
    51.f, 60.f, 69.f, 80.f, 103.f, 113.f, 120.f, 103.f,
    61.f, 55.f, 56.f, 62.f,  77.f,  92.f, 101.f,  99.f
};
// Correctly-rounded reciprocals (compile-time IEEE division), same layout.
__device__ __align__(16) const float RYQT[64] = {
    1.f/16.f, 1.f/12.f, 1.f/14.f, 1.f/14.f, 1.f/18.f,  1.f/24.f,  1.f/49.f,  1.f/72.f,
    1.f/11.f, 1.f/12.f, 1.f/13.f, 1.f/17.f, 1.f/22.f,  1.f/35.f,  1.f/64.f,  1.f/92.f,
    1.f/10.f, 1.f/14.f, 1.f/16.f, 1.f/22.f, 1.f/37.f,  1.f/55.f,  1.f/78.f,  1.f/95.f,
    1.f/16.f, 1.f/19.f, 1.f/24.f, 1.f/29.f, 1.f/56.f,  1.f/64.f,  1.f/87.f,  1.f/98.f,
    1.f/24.f, 1.f/26.f, 1.f/40.f, 1.f/51.f, 1.f/68.f,  1.f/81.f,  1.f/103.f, 1.f/112.f,
    1.f/40.f, 1.f/58.f, 1.f/57.f, 1.f/87.f, 1.f/109.f, 1.f/104.f, 1.f/121.f, 1.f/100.f,
    1.f/51.f, 1.f/60.f, 1.f/69.f, 1.f/80.f, 1.f/103.f, 1.f/113.f, 1.f/120.f, 1.f/103.f,
    1.f/61.f, 1.f/55.f, 1.f/56.f, 1.f/62.f, 1.f/77.f,  1.f/92.f,  1.f/101.f, 1.f/99.f
};
// Chroma table (symmetric) + reciprocals.
__device__ __align__(16) const float CQ[64] = {
    17.f, 18.f, 24.f, 47.f, 99.f, 99.f, 99.f, 99.f,
    18.f, 21.f, 26.f, 66.f, 99.f, 99.f, 99.f, 99.f,
    24.f, 26.f, 56.f, 99.f, 99.f, 99.f, 99.f, 99.f,
    47.f, 66.f, 99.f, 99.f, 99.f, 99.f, 99.f, 99.f,
    99.f, 99.f, 99.f, 99.f, 99.f, 99.f, 99.f, 99.f,
    99.f, 99.f, 99.f, 99.f, 99.f, 99.f, 99.f, 99.f,
    99.f, 99.f, 99.f, 99.f, 99.f, 99.f, 99.f, 99.f,
    99.f, 99.f, 99.f, 99.f, 99.f, 99.f, 99.f, 99.f
};
__device__ __align__(16) const float RCQ[64] = {
    1.f/17.f, 1.f/18.f, 1.f/24.f, 1.f/47.f, 1.f/99.f, 1.f/99.f, 1.f/99.f, 1.f/99.f,
    1.f/18.f, 1.f/21.f, 1.f/26.f, 1.f/66.f, 1.f/99.f, 1.f/99.f, 1.f/99.f, 1.f/99.f,
    1.f/24.f, 1.f/26.f, 1.f/56.f, 1.f/99.f, 1.f/99.f, 1.f/99.f, 1.f/99.f, 1.f/99.f,
    1.f/47.f, 1.f/66.f, 1.f/99.f, 1.f/99.f, 1.f/99.f, 1.f/99.f, 1.f/99.f, 1.f/99.f,
    1.f/99.f, 1.f/99.f, 1.f/99.f, 1.f/99.f, 1.f/99.f, 1.f/99.f, 1.f/99.f, 1.f/99.f,
    1.f/99.f, 1.f/99.f, 1.f/99.f, 1.f/99.f, 1.f/99.f, 1.f/99.f, 1.f/99.f, 1.f/99.f,
    1.f/99.f, 1.f/99.f, 1.f/99.f, 1.f/99.f, 1.f/99.f, 1.f/99.f, 1.f/99.f, 1.f/99.f,
    1.f/99.f, 1.f/99.f, 1.f/99.f, 1.f/99.f, 1.f/99.f, 1.f/99.f, 1.f/99.f, 1.f/99.f
};

// fma helpers: scalar -> v_fma_f32, f32x2 -> v_pk_fma_f32 (bit-identical per half)
__device__ __forceinline__ float gfma(float a, float b, float c) { return fmaf(a, b, c); }
__device__ __forceinline__ f32x2 gfma(f32x2 a, f32x2 b, f32x2 c) { return __builtin_elementwise_fma(a, b, c); }
__device__ __forceinline__ f32x2 gfma(float a, f32x2 b, f32x2 c) { return __builtin_elementwise_fma((f32x2){a, a}, b, c); }

// clamp to [0,1] via v_med3_f32 — value-identical to fminf(fmaxf(x,0),1) for non-NaN
__device__ __forceinline__ float clamp01(float x) { return __builtin_amdgcn_fmed3f(x, 0.f, 1.f); }
__device__ __forceinline__ f32x2 clamp2(f32x2 v) { return (f32x2){clamp01(v.x), clamp01(v.y)}; }

// 8-point DCT-II butterfly (frozen arithmetic since R4; elementwise for vectors).
template <typename T>
__device__ __forceinline__ void dct8(const T x[8], T X[8]) {
    const T a0 = x[0] + x[7], a1 = x[1] + x[6], a2 = x[2] + x[5], a3 = x[3] + x[4];
    const T d0 = x[0] - x[7], d1 = x[1] - x[6], d2 = x[2] - x[5], d3 = x[3] - x[4];
    const T e0 = a0 + a3, e1 = a1 + a2, f0 = a0 - a3, f1 = a1 - a2;
    X[0] = K4 * (e0 + e1);
    X[4] = K4 * (e0 - e1);
    X[2] = gfma(K6, f1, K2 * f0);
    X[6] = gfma(-K2, f1, K6 * f0);
    X[1] = gfma(K7, d3, gfma(K5, d2, gfma(K3, d1, K1 * d0)));
    X[3] = gfma(-K5, d3, gfma(-K1, d2, gfma(-K7, d1, K3 * d0)));
    X[5] = gfma(K3, d3, gfma(K7, d2, gfma(-K1, d1, K5 * d0)));
    X[7] = gfma(-K1, d3, gfma(K3, d2, gfma(-K5, d1, K7 * d0)));
}

template <typename T>
__device__ __forceinline__ void idct8(const T X[8], T x[8]) {
    const T g0 = K4 * (X[0] + X[4]);
    const T g1 = K4 * (X[0] - X[4]);
    const T E0 = gfma(K6, X[6], gfma(K2, X[2], g0));
    const T E1 = gfma(-K2, X[6], gfma(K6, X[2], g1));
    const T E2 = gfma(K2, X[6], gfma(-K6, X[2], g1));
    const T E3 = gfma(-K6, X[6], gfma(-K2, X[2], g0));
    const T O0 = gfma(K7, X[7], gfma(K5, X[5], gfma(K3, X[3], K1 * X[1])));
    const T O1 = gfma(-K5, X[7], gfma(-K1, X[5], gfma(-K7, X[3], K3 * X[1])));
    const T O2 = gfma(K3, X[7], gfma(K7, X[5], gfma(-K1, X[3], K5 * X[1])));
    const T O3 = gfma(-K1, X[7], gfma(K3, X[5], gfma(-K5, X[3], K7 * X[1])));
    x[0] = E0 + O0;  x[7] = E0 - O0;
    x[1] = E1 + O1;  x[6] = E1 - O1;
    x[2] = E2 + O2;  x[5] = E2 - O2;
    x[3] = E3 + O3;  x[4] = E3 - O3;
}

// Exact RN(s/qt) via Markstein refinement (bit-identical to IEEE div) + rint + dequant.
__device__ __forceinline__ f32x2 quant2(f32x2 sv, f32x2 qt, f32x2 rq) {
    const f32x2 q0 = sv * rq;
    const f32x2 e  = gfma(-qt, q0, sv);
    const f32x2 q  = gfma(rq, e, q0);
    const f32x2 n  = {rintf(q.x), rintf(q.y)};
    return n * qt;
}

// Scheduler-only ordering point (R8/R10-verified correct for the wave-local
// LDS union: per-wave in-order DS pipe supplies runtime ordering).
#define SB() __builtin_amdgcn_sched_barrier(0)

#define YW2 132   // Y plane stride (floats):  132%32=4 -> all phases <=2-way (free)
#define CW2 132   // chroma plane stride (f32x2)

// 128-wide x 8-tall strip per wave; each lane owns the pixel PAIR (cols 2l,2l+1)
// -> f32x2 global loads/stores land directly in packed-column layout (no transpose),
// and the whole Y path + Y row pass run as v_pk_fma over the pair.
__global__ __launch_bounds__(256, 4) void diffjpeg_kernel(const float* __restrict__ in,
                                                          float* __restrict__ out)
{
    // PER-WAVE private chunk: chroma view [8][132] f32x2 = 8448 B; Y view (float,
    // stride 132, 4224 B) aliases the same chunk -> union is wave-local.
    // Block total 33792 B -> 4 blocks/CU (16 waves/CU).
    __shared__ __align__(16) f32x2 lds[4][8][CW2];

    const int t  = threadIdx.x;
    const int l  = t & 63;
    const int wv = t >> 6;
    const int rr = l & 7;           // row-pass: within-block row
    const int bc = l >> 3;          // row-pass: first block index (jobs bc and bc+8)

    f32x2 (*plc)[CW2] = lds[wv];           // chroma view
    float* ply = (float*)&lds[wv][0][0];   // Y view (aliases chunk)

    // 2048 blocks: 64 per image (16 row-slabs of 32 x 4 col-tiles of 128).
    const int bid  = blockIdx.x;
    const int img  = bid >> 6;
    const int rem  = bid & 63;
    const int trow = rem >> 2;       // 0..15
    const int tcol = rem & 3;        // 0..3
    const size_t HW = (size_t)512 * 512;
    const size_t sbase = (size_t)img * 3 * HW + (size_t)(trow * 32 + wv * 8) * 512 + (size_t)(tcol * 128);
    const float* __restrict__ pin  = in  + sbase + 2 * l;
    float* __restrict__       pout = out + sbase + 2 * l;

    // ---- Load pixel-pair columns (f32x2, 512B/instr coalesced) ----
    f32x2 rv[8], gv[8], bv[8];
    #pragma unroll
    for (int x = 0; x < 8; ++x) rv[x] = *(const f32x2*)(pin + (size_t)x * 512);
    #pragma unroll
    for (int x = 0; x < 8; ++x) gv[x] = *(const f32x2*)(pin + HW + (size_t)x * 512);
    #pragma unroll
    for (int x = 0; x < 8; ++x) bv[x] = *(const f32x2*)(pin + 2 * HW + (size_t)x * 512);

    // ---- RGB->YCbCr, packed over the pixel pair (per-component arithmetic
    //      identical to R7: cb = fma(.564, fma(255,b,-Y), -.5), etc.) ----
    f32x2 yv[8], cbv[8], crv[8];
    #pragma unroll
    for (int x = 0; x < 8; ++x) {
        const f32x2 r = clamp2(rv[x]);
        const f32x2 g = clamp2(gv[x]);
        const f32x2 b = clamp2(bv[x]);
        const f32x2 Y = gfma(76.245f, r, gfma(149.685f, g, 29.07f * b));  // 255*y
        yv[x] = Y - 128.f;
        cbv[x] = gfma(0.564f, gfma(255.f, b, -Y), (f32x2){-0.5f, -0.5f});
        crv[x] = gfma(0.713f, gfma(255.f, r, -Y), (f32x2){-0.5f, -0.5f});
    }

    // ==================== Y plane (packed pixel-pair), full chain ====================
    f32x2 sy[8];
    {
        // column DCT -> LDS (8B contiguous per lane)
        f32x2 X0[8];
        dct8(yv, X0);
        #pragma unroll
        for (int u = 0; u < 8; ++u) *(f32x2*)&ply[u * YW2 + 2 * l] = X0[u];
        SB();

        // row pass: TWO blocks (bc, bc+8) packed per lane — row DCT + quant + row IDCT
        {
            const float4* yq4  = (const float4*)&YQT[rr * 8];
            const float4* ryq4 = (const float4*)&RYQT[rr * 8];
            const float4 yqa = yq4[0],  yqb = yq4[1];
            const float4 rya = ryq4[0], ryb = ryq4[1];
            const float yq[8]  = {yqa.x, yqa.y, yqa.z, yqa.w, yqb.x, yqb.y, yqb.z, yqb.w};
            const float ryq[8] = {rya.x, rya.y, rya.z, rya.w, ryb.x, ryb.y, ryb.z, ryb.w};

            float* base1 = ply + rr * YW2 + bc * 8;   // job 1: block bc
            f32x2 T[8];
            #pragma unroll
            for (int y = 0; y < 8; ++y) T[y] = (f32x2){base1[y], base1[y + 64]};
            f32x2 S[8];
            dct8(T, S);
            f32x2 Dq[8];
            #pragma unroll
            for (int v = 0; v < 8; ++v)
                Dq[v] = quant2(S[v], (f32x2){yq[v], yq[v]}, (f32x2){ryq[v], ryq[v]});
            f32x2 o[8];
            idct8(Dq, o);
            #pragma unroll
            for (int y = 0; y < 8; ++y) { base1[y] = o[y].x; base1[y + 64] = o[y].y; }
        }
        SB();

        // column IDCT -> registers
        f32x2 Xy[8];
        #pragma unroll
        for (int u = 0; u < 8; ++u) Xy[u] = *(f32x2*)&ply[u * YW2 + 2 * l];
        idct8(Xy, sy);
    }
    SB();   // WAR (wave-local): Y col reads ordered before chroma writes reuse the chunk

    // ==================== Chroma (2 pixels x {cb,cr} f32x2) ====================
    f32x2 sc0[8], sc1[8];
    {
        // column DCT packed over the pixel pair, repacked to {cb,cr} at LDS write
        f32x2 XB[8], XR[8];
        dct8(cbv, XB);
        dct8(crv, XR);
        #pragma unroll
        for (int u = 0; u < 8; ++u)
            *(float4*)&plc[u][2 * l] = make_float4(XB[u].x, XR[u].x, XB[u].y, XR[u].y);
        SB();

        // row pass: two jobs (blocks bc, bc+8), each f32x2 {cb,cr}
        {
            const float4* cq4  = (const float4*)&CQ[rr * 8];
            const float4* rcq4 = (const float4*)&RCQ[rr * 8];
            const float4 cqa = cq4[0],  cqb = cq4[1];
            const float4 rca = rcq4[0], rcb4 = rcq4[1];
            const float cq[8]  = {cqa.x, cqa.y, cqa.z, cqa.w, cqb.x, cqb.y, cqb.z, cqb.w};
            const float rcq[8] = {rca.x, rca.y, rca.z, rca.w, rcb4.x, rcb4.y, rcb4.z, rcb4.w};

            f32x2* cbase = &plc[rr][bc * 8];
            #pragma unroll
            for (int j = 0; j < 2; ++j) {
                float4* rp = (float4*)(cbase + j * 64);
                const float4 p0 = rp[0], p1 = rp[1], p2 = rp[2], p3 = rp[3];
                const f32x2 T[8] = {{p0.x, p0.y}, {p0.z, p0.w}, {p1.x, p1.y}, {p1.z, p1.w},
                                    {p2.x, p2.y}, {p2.z, p2.w}, {p3.x, p3.y}, {p3.z, p3.w}};
                f32x2 S[8];
                dct8(T, S);
                f32x2 Dq[8];
                #pragma unroll
                for (int v = 0; v < 8; ++v)
                    Dq[v] = quant2(S[v], (f32x2){cq[v], cq[v]}, (f32x2){rcq[v], rcq[v]});
                f32x2 o[8];
                idct8(Dq, o);
                rp[0] = make_float4(o[0].x, o[0].y, o[1].x, o[1].y);
                rp[1] = make_float4(o[2].x, o[2].y, o[3].x, o[3].y);
                rp[2] = make_float4(o[4].x, o[4].y, o[5].x, o[5].y);
                rp[3] = make_float4(o[6].x, o[6].y, o[7].x, o[7].y);
            }
        }
        SB();

        // column IDCT -> registers (both pixels)
        f32x2 Xc0[8], Xc1[8];
        #pragma unroll
        for (int u = 0; u < 8; ++u) {
            const float4 q = *(const float4*)&plc[u][2 * l];
            Xc0[u] = (f32x2){q.x, q.y};
            Xc1[u] = (f32x2){q.z, q.w};
        }
        idct8(Xc0, sc0);
        idct8(Xc1, sc1);
    }

    // ---- YCbCr->RGB + clip + nt f32x2 store (per-pixel arithmetic identical to R7) ----
    {
        constexpr float inv255 = 1.0f / 255.0f;
        constexpr float Kr = 0.504711754f;
        constexpr float Kg = 0.499886280f;
        constexpr float Kb = 0.505437240f;
        #pragma unroll
        for (int x = 0; x < 8; ++x) {
            const float y0 = sy[x].x, y1 = sy[x].y;
            const float cb0 = sc0[x].x, cr0 = sc0[x].y;
            const float cb1 = sc1[x].x, cr1 = sc1[x].y;
            const f32x2 in0 = gfma((f32x2){1.403f, 1.773f}, (f32x2){cr0, cb0}, (f32x2){y0, y0});
            const f32x2 rb0 = gfma(inv255, in0, (f32x2){Kr, Kb});
            const float g0  = fmaf(inv255, fmaf(-0.714f, cr0, fmaf(-0.344f, cb0, y0)), Kg);
            const f32x2 in1 = gfma((f32x2){1.403f, 1.773f}, (f32x2){cr1, cb1}, (f32x2){y1, y1});
            const f32x2 rb1 = gfma(inv255, in1, (f32x2){Kr, Kb});
            const float g1  = fmaf(inv255, fmaf(-0.714f, cr1, fmaf(-0.344f, cb1, y1)), Kg);
            const f32x2 Rst = (f32x2){clamp01(rb0.x), clamp01(rb1.x)};
            const f32x2 Gst = (f32x2){clamp01(g0),   clamp01(g1)};
            const f32x2 Bst = (f32x2){clamp01(rb0.y), clamp01(rb1.y)};
            __builtin_nontemporal_store(Rst, (f32x2*)(pout + (size_t)x * 512));
            __builtin_nontemporal_store(Gst, (f32x2*)(pout + HW + (size_t)x * 512));
            __builtin_nontemporal_store(Bst, (f32x2*)(pout + 2 * HW + (size_t)x * 512));
        }
    }
}

extern "C" void kernel_launch(void* const* d_in, const int* in_sizes, int n_in,
                              void* d_out, int out_size, void* d_ws, size_t ws_size,
                              hipStream_t stream) {
    const float* in = (const float*)d_in[0];
    float* out = (float*)d_out;
    const int B = in_sizes[0] / (3 * 512 * 512);   // 32
    const int grid = B * 64;                        // 64 blocks (128x32 tiles) per image
    diffjpeg_kernel<<<grid, 256, 0, stream>>>(in, out);
}